// Round 6
// baseline (51.952 us; speedup 1.0000x reference)
//
#include <hip/hip_runtime.h>

// Problem constants (match reference)
#define NB 32768
#define ND 512
#define NK 10

#define LEFTB (-10.0f)
#define RIGHTB (10.0f)
#define ROWS 8
#define BX 1024     // grid = (BX, 4); block = 128 threads = 128 features
#define FPB 128     // features per block

// ---------------------------------------------------------------------------
// Workspace layout (floats):
//   E     [ 9][512]          internal knots cw[1..9] (register bin search)
//   GCWCH [11][512] float2   {cw_k, ch_k} knot pairs
//   GDD   [11][512]          d_k
//   part  [NB][32]           per-row partial sums for logdet
// ---------------------------------------------------------------------------

__global__ void rqs_precompute(const float* __restrict__ uw,
                               const float* __restrict__ uh,
                               const float* __restrict__ ud,
                               float* __restrict__ ws) {
    int f = blockIdx.x * blockDim.x + threadIdx.x;
    if (f >= ND) return;

    float* E = ws;                                // 9*512
    float2* GCWCH = (float2*)(ws + 9 * ND);       // 11*512 float2
    float* GDD = ws + 9 * ND + 22 * ND;           // 11*512

    float cw[NK + 1], ch[NK + 1], dd[NK + 1];

    // ---- widths -> x-knots ----
    {
        float u[NK];
        float m = -1e30f;
#pragma unroll
        for (int k = 0; k < NK; ++k) { u[k] = uw[f * NK + k]; m = fmaxf(m, u[k]); }
        float s = 0.0f;
#pragma unroll
        for (int k = 0; k < NK; ++k) { u[k] = expf(u[k] - m); s += u[k]; }
        float inv = 1.0f / s;
        float c = 0.0f;
        cw[0] = LEFTB;
#pragma unroll
        for (int k = 0; k < NK; ++k) {
            float wk = 1e-3f + (1.0f - 1e-3f * NK) * (u[k] * inv);
            c += wk;
            cw[k + 1] = (RIGHTB - LEFTB) * c + LEFTB;
        }
        cw[NK] = RIGHTB;
    }
    // ---- heights -> y-knots ----
    {
        float u[NK];
        float m = -1e30f;
#pragma unroll
        for (int k = 0; k < NK; ++k) { u[k] = uh[f * NK + k]; m = fmaxf(m, u[k]); }
        float s = 0.0f;
#pragma unroll
        for (int k = 0; k < NK; ++k) { u[k] = expf(u[k] - m); s += u[k]; }
        float inv = 1.0f / s;
        float c = 0.0f;
        ch[0] = LEFTB;
#pragma unroll
        for (int k = 0; k < NK; ++k) {
            float hk = 1e-3f + (1.0f - 1e-3f * NK) * (u[k] * inv);
            c += hk;
            ch[k + 1] = (RIGHTB - LEFTB) * c + LEFTB;
        }
        ch[NK] = RIGHTB;
    }
    // ---- derivatives: boundary pads are exactly 1.0 ----
    dd[0] = 1.0f;
    dd[NK] = 1.0f;
#pragma unroll
    for (int k = 1; k < NK; ++k) {
        float v = ud[f * (NK - 1) + (k - 1)];
        dd[k] = 1e-3f + (fmaxf(v, 0.0f) + log1pf(expf(-fabsf(v))));
    }

    // ---- store ----
#pragma unroll
    for (int j = 0; j < 9; ++j) E[j * ND + f] = cw[j + 1];
#pragma unroll
    for (int k = 0; k <= NK; ++k) {
        GCWCH[k * ND + f] = make_float2(cw[k], ch[k]);
        GDD[k * ND + f] = dd[k];
    }
}

// ---------------------------------------------------------------------------
// Main transform. Block = 128 threads = 128 features (quarter selected by
// blockIdx.y). LDS [knot][FPB] layout: plane stride 128 dwords (multiple of
// 32 banks) -> per-lane idx gather is conflict-free; knot k/k+1 pairs are
// 1024 B / 512 B apart -> compiler fuses into ds_read2_b64 / ds_read2_b32.
// ---------------------------------------------------------------------------
__global__ __launch_bounds__(128) void rqs_main(const float* __restrict__ X,
                                                const float* __restrict__ ws,
                                                float* __restrict__ Y,
                                                float* __restrict__ part) {
    const int t = threadIdx.x;
    const int q = blockIdx.y;        // feature quarter 0..3
    const int f = q * FPB + t;

    const float* E = ws;
    const float2* GCWCH = (const float2*)(ws + 9 * ND);
    const float* GDD = ws + 9 * ND + 22 * ND;

    __shared__ float2 sCWCH[NK + 1][FPB];  // 11264 B
    __shared__ float sDD[NK + 1][FPB];     //  5632 B

#pragma unroll
    for (int k = 0; k <= NK; ++k) {
        sCWCH[k][t] = GCWCH[k * ND + f];
        sDD[k][t] = GDD[k * ND + f];
    }
    float e[9];
#pragma unroll
    for (int j = 0; j < 9; ++j) e[j] = E[j * ND + f];
    __syncthreads();

    for (int r0 = blockIdx.x * ROWS; r0 < NB; r0 += gridDim.x * ROWS) {
        float xs[ROWS], ys[ROWS], ls[ROWS];
#pragma unroll
        for (int i = 0; i < ROWS; ++i)
            xs[i] = __builtin_nontemporal_load(&X[(r0 + i) * ND + f]);

#pragma unroll
        for (int i = 0; i < ROWS; ++i) {
            float x = xs[i];
            bool inside = (x >= LEFTB) && (x <= RIGHTB);
            float xc = fminf(fmaxf(x, LEFTB), RIGHTB);

            int idx = 0;
#pragma unroll
            for (int j = 0; j < 9; ++j) idx += (xc >= e[j]) ? 1 : 0;

            float2 c0 = sCWCH[idx][t];      // {cw_k,   ch_k}
            float2 c1 = sCWCH[idx + 1][t];  // {cw_k+1, ch_k+1}
            float dk = sDD[idx][t];
            float dk1 = sDD[idx + 1][t];

            float w = c1.x - c0.x;
            float rw = __builtin_amdgcn_rcpf(w);   // w >= 0.02 always
            float h = c1.y - c0.y;
            float delta = h * rw;

            float theta = (xc - c0.x) * rw;
            float omt = 1.0f - theta;
            float t1m = theta * omt;
            float th2 = theta * theta;

            float num = h * fmaf(delta, th2, dk * t1m);
            float den = fmaf(dk + dk1 - 2.0f * delta, t1m, delta);
            float rden = __builtin_amdgcn_rcpf(den);  // den > 0 always
            float y = fmaf(num, rden, c0.y);

            float dnum = delta * delta *
                         (fmaf(dk1, th2, 2.0f * delta * t1m) + dk * omt * omt);
            float lad = __logf(dnum * rden * rden);  // log(dnum) - 2 log(den)

            ys[i] = inside ? y : x;
            ls[i] = inside ? lad : 0.0f;
        }

#pragma unroll
        for (int i = 0; i < ROWS; ++i)
            __builtin_nontemporal_store(ys[i], &Y[(r0 + i) * ND + f]);

        // 4-level xor reduce (DPP row ops) -> 8 partials per row-quarter
#pragma unroll
        for (int off = 1; off <= 8; off <<= 1) {
#pragma unroll
            for (int i = 0; i < ROWS; ++i) ls[i] += __shfl_xor(ls[i], off, 64);
        }
        if ((t & 15) == 0) {
            int g = q * 8 + (t >> 4);  // 0..31 across the four quarters
#pragma unroll
            for (int i = 0; i < ROWS; ++i) part[(r0 + i) * 32 + g] = ls[i];
        }
    }
}

// ---------------------------------------------------------------------------
// logdet = sum of 32 partials per row. 8 threads per row, float4.
// ---------------------------------------------------------------------------
__global__ __launch_bounds__(256) void rqs_reduce(const float* __restrict__ part,
                                                  float* __restrict__ logdet) {
    int j = blockIdx.x * 256 + threadIdx.x;
    int row = j >> 3;
    int sub = j & 7;
    float4 v = ((const float4*)part)[row * 8 + sub];
    float s = (v.x + v.y) + (v.z + v.w);
    s += __shfl_xor(s, 1, 64);
    s += __shfl_xor(s, 2, 64);
    s += __shfl_xor(s, 4, 64);
    if (sub == 0) logdet[row] = s;
}

extern "C" void kernel_launch(void* const* d_in, const int* in_sizes, int n_in,
                              void* d_out, int out_size, void* d_ws, size_t ws_size,
                              hipStream_t stream) {
    const float* x  = (const float*)d_in[0];
    const float* uw = (const float*)d_in[1];
    const float* uh = (const float*)d_in[2];
    const float* ud = (const float*)d_in[3];

    float* out = (float*)d_out;
    float* Y = out;                              // [NB*ND]
    float* logdet = out + (size_t)NB * ND;       // [NB]

    float* ws = (float*)d_ws;                    // tables: (9+22+11)*512 floats (84 KB)
    float* part = ws + (9 + 22 + 11) * ND;       // NB*32 floats (4 MB)

    hipLaunchKernelGGL(rqs_precompute, dim3(2), dim3(256), 0, stream,
                       uw, uh, ud, ws);
    hipLaunchKernelGGL(rqs_main, dim3(BX, 4), dim3(128), 0, stream,
                       x, ws, Y, part);
    hipLaunchKernelGGL(rqs_reduce, dim3(NB * 8 / 256), dim3(256), 0, stream,
                       part, logdet);
}